// Round 5
// baseline (106.428 us; speedup 1.0000x reference)
//
#include <hip/hip_runtime.h>
#include <hip/hip_bf16.h>

#define D  16
#define NB 262144
#define NG 20000
#define ROWPITCH 36   // dwords per staged row (32 data + 4 pad, keeps 16B align)
#define ZPITCH   20   // dwords per z row in transpose buffer (16 data + 4 pad)

typedef __attribute__((ext_vector_type(8))) short bf16x8;
typedef __attribute__((ext_vector_type(4))) float f32x4;
typedef __attribute__((ext_vector_type(2))) float f32x2;

// ---------------------------------------------------------------------------
// Prep kernel, 80 blocks:
//   blocks 0..78 : per-gene MLP table T[g] (one thread per gene)
//   block  79    : build M[n,k,j] = sum_m BD[n,m]*BW[n,m,k]*BW[m,n,j],
//                  repack to RNE-bf16 MFMA B-fragments, fold Boff into bc1.
// ---------------------------------------------------------------------------
__global__ void __launch_bounds__(256)
prep_kernel(const float* __restrict__ emb,
            const float* __restrict__ W1, const float* __restrict__ b1,
            const float* __restrict__ W2, const float* __restrict__ b2,
            const float* __restrict__ W3, const float* __restrict__ b3,
            const float* __restrict__ BW, const float* __restrict__ BD,
            const float* __restrict__ Wc1, const float* __restrict__ bc1,
            const float* __restrict__ Boff,
            float* __restrict__ T, short* __restrict__ Bhi,
            float* __restrict__ bc1p) {
    __shared__ float smem[8704];   // bw[0,4096) | bd[4096,4352) | Mm[4352,8704) pitch 17
    int tid = threadIdx.x;
    int blk = blockIdx.x;

    if (blk < 79) {
        // ---- gene MLP ----
        int g = blk * 256 + tid;
        if (g >= NG) return;
        float h[D], t[D];
        const float4* ep = (const float4*)(emb + (size_t)g * D);
        float4 v0 = ep[0], v1 = ep[1], v2 = ep[2], v3 = ep[3];
        h[0]=v0.x; h[1]=v0.y; h[2]=v0.z; h[3]=v0.w;
        h[4]=v1.x; h[5]=v1.y; h[6]=v1.z; h[7]=v1.w;
        h[8]=v2.x; h[9]=v2.y; h[10]=v2.z; h[11]=v2.w;
        h[12]=v3.x; h[13]=v3.y; h[14]=v3.z; h[15]=v3.w;
        #pragma unroll
        for (int i = 0; i < D; ++i) {
            float a = b1[i];
            #pragma unroll
            for (int d = 0; d < D; ++d) a = fmaf(W1[i * D + d], h[d], a);
            t[i] = fmaxf(a, 0.f);
        }
        #pragma unroll
        for (int i = 0; i < D; ++i) {
            float a = b2[i];
            #pragma unroll
            for (int d = 0; d < D; ++d) a = fmaf(W2[i * D + d], t[d], a);
            h[i] = fmaxf(a, 0.f);
        }
        #pragma unroll
        for (int i = 0; i < D; ++i) {
            float a = b3[i];
            #pragma unroll
            for (int d = 0; d < D; ++d) a = fmaf(W3[i * D + d], h[d], a);
            t[i] = a;
        }
        float4* tp = (float4*)(T + (size_t)g * D);
        tp[0] = make_float4(t[0], t[1], t[2], t[3]);
        tp[1] = make_float4(t[4], t[5], t[6], t[7]);
        tp[2] = make_float4(t[8], t[9], t[10], t[11]);
        tp[3] = make_float4(t[12], t[13], t[14], t[15]);
        return;
    }

    // ---- build block ----
    float* bwS = smem;
    float* bdS = smem + 4096;
    float* MmS = smem + 4352;   // [256][17]: Mm[kk][n] at kk*17+n
    #pragma unroll
    for (int i = 0; i < 16; ++i) bwS[tid + 256 * i] = BW[tid + 256 * i];
    bdS[tid] = BD[tid];
    __syncthreads();

    // thread (n,j): acc[k] = M[n][k][j], vectorized over k via b128 LDS reads
    int n = tid >> 4, j = tid & 15;
    float acc[16];
    #pragma unroll
    for (int k = 0; k < 16; ++k) acc[k] = 0.f;
    #pragma unroll
    for (int m = 0; m < 16; ++m) {
        float sw = bdS[n * 16 + m] * bwS[(m * 16 + n) * 16 + j];
        const f32x4* w1 = (const f32x4*)&bwS[(n * 16 + m) * 16];
        #pragma unroll
        for (int q = 0; q < 4; ++q) {
            f32x4 w = w1[q];
            acc[4 * q + 0] = fmaf(sw, w.x, acc[4 * q + 0]);
            acc[4 * q + 1] = fmaf(sw, w.y, acc[4 * q + 1]);
            acc[4 * q + 2] = fmaf(sw, w.z, acc[4 * q + 2]);
            acc[4 * q + 3] = fmaf(sw, w.w, acc[4 * q + 3]);
        }
    }
    #pragma unroll
    for (int k = 0; k < 16; ++k) MmS[(k * 16 + j) * 17 + n] = acc[k];
    __syncthreads();

    // repack to RNE-bf16 MFMA B fragments (same layout as verified rounds 2-4)
    for (int idx = tid; idx < 512; idx += 256) {
        int s = idx >> 6, lane = idx & 63;
        int q = lane >> 4, nn = lane & 15;
        unsigned hw[4];
        #pragma unroll
        for (int w = 0; w < 4; ++w) {
            int kk0 = s * 32 + q * 8 + 2 * w;
            float2 p = make_float2(MmS[kk0 * 17 + nn], MmS[(kk0 + 1) * 17 + nn]);
            __hip_bfloat162 hv = __float22bfloat162_rn(p);   // v0 -> low16, v1 -> high16
            hw[w] = *(unsigned*)&hv;
        }
        ((uint4*)Bhi)[idx] = make_uint4(hw[0], hw[1], hw[2], hw[3]);
    }

    if (tid < 16) {
        float a = bc1[tid];
        #pragma unroll
        for (int nn = 0; nn < 16; ++nn) a += Wc1[tid * 16 + nn] * Boff[nn];
        bc1p[tid] = a;
    }
}

// ---------------------------------------------------------------------------
// Main kernel: wave handles 64 rows (4 MFMA tiles). BARRIER-FREE: every LDS
// region is private to one wave (lockstep + in-order DS pipeline give the
// needed ordering); transpose buffer aliases the wave's own staging region.
// Phase 1: each lane stages its own row's T data (pitch 36).
// Phase 2: A = RNE-bf16(e0*e1) via v_cvt_pk_bf16_f32; 1 MFMA per K-slice.
// Phase 3: in-wave LDS transpose (pitch 20, b128 reads) + pk-vector head.
// ---------------------------------------------------------------------------
__global__ void __launch_bounds__(256)
main_kernel(const int* __restrict__ x, const float* __restrict__ phenos,
            const float* __restrict__ T, const short* __restrict__ Bhi,
            const float* __restrict__ bc1p, const float* __restrict__ Wc1,
            const float* __restrict__ Wc2, const float* __restrict__ bc2,
            float* __restrict__ out) {
    __shared__ float smem[9216];           // 4 waves x (64 rows x 36 dwords)
    int tid  = threadIdx.x;
    int wave = tid >> 6, lane = tid & 63;
    int quad = lane >> 4, nl = lane & 15;
    long base = (long)blockIdx.x * 256 + wave * 64;
    float* stg = smem + wave * 2304;       // this wave's private region

    // resident B fragments (uniform, L2-hot)
    bf16x8 bh[8];
    #pragma unroll
    for (int s = 0; s < 8; ++s) bh[s] = ((const bf16x8*)Bhi)[s * 64 + lane];

    // ---- phase 1: stage own row ----
    long r = base + lane;
    int2 g = ((const int2*)x)[r];
    {
        const f32x4* p0 = (const f32x4*)(T + g.x * 16);
        const f32x4* p1 = (const f32x4*)(T + g.y * 16);
        f32x4 c0 = p0[0], c1 = p0[1], c2 = p0[2], c3 = p0[3];
        f32x4 c4 = p1[0], c5 = p1[1], c6 = p1[2], c7 = p1[3];
        f32x4* wp = (f32x4*)(stg + lane * ROWPITCH);
        wp[0] = c0; wp[1] = c1; wp[2] = c2; wp[3] = c3;
        wp[4] = c4; wp[5] = c5; wp[6] = c6; wp[7] = c7;
    }

    // ---- phase 2: MFMA tile loop (reads only this wave's rows) ----
    f32x4 acc[4];
    #pragma unroll
    for (int t = 0; t < 4; ++t) acc[t] = (f32x4){0.f, 0.f, 0.f, 0.f};
    const int par = quad >> 1;          // e0 parity for this quad
    const int eo  = (quad & 1) * 8;     // e1 half for this quad

    #pragma unroll
    for (int t = 0; t < 4; ++t) {
        const float* rowp = stg + (t * 16 + nl) * ROWPITCH;
        float ev[8];
        #pragma unroll
        for (int s = 0; s < 8; ++s) ev[s] = rowp[2 * s + par];
        f32x4 e1a = *(const f32x4*)(rowp + 16 + eo);
        f32x4 e1b = *(const f32x4*)(rowp + 20 + eo);
        float2 e1p[4] = {make_float2(e1a.x, e1a.y), make_float2(e1a.z, e1a.w),
                         make_float2(e1b.x, e1b.y), make_float2(e1b.z, e1b.w)};

        #pragma unroll
        for (int s = 0; s < 8; ++s) {
            unsigned aw[4];
            #pragma unroll
            for (int w = 0; w < 4; ++w) {
                float2 p = make_float2(ev[s] * e1p[w].x, ev[s] * e1p[w].y); // v_pk_mul_f32
                __hip_bfloat162 hv = __float22bfloat162_rn(p);              // v_cvt_pk_bf16_f32
                aw[w] = *(unsigned*)&hv;
            }
            bf16x8 ah = __builtin_bit_cast(bf16x8, make_uint4(aw[0], aw[1], aw[2], aw[3]));
            acc[t] = __builtin_amdgcn_mfma_f32_16x16x32_bf16(ah, bh[s], acc[t], 0, 0, 0);
        }
    }

    // ---- phase 3: in-wave transpose (aliases own staging region) + head ----
    float* zb = stg;                     // [64][ZPITCH], 1280 <= 2304 dwords
    #pragma unroll
    for (int t = 0; t < 4; ++t) {
        #pragma unroll
        for (int reg = 0; reg < 4; ++reg)
            zb[(t * 16 + quad * 4 + reg) * ZPITCH + nl] = acc[t][reg];
    }

    const float* zr = zb + lane * ZPITCH;
    f32x4 q0 = *(const f32x4*)(zr + 0);
    f32x4 q1 = *(const f32x4*)(zr + 4);
    f32x4 q2 = *(const f32x4*)(zr + 8);
    f32x4 q3 = *(const f32x4*)(zr + 12);
    f32x2 zv2[8] = {(f32x2){q0.x, q0.y}, (f32x2){q0.z, q0.w},
                    (f32x2){q1.x, q1.y}, (f32x2){q1.z, q1.w},
                    (f32x2){q2.x, q2.y}, (f32x2){q2.z, q2.w},
                    (f32x2){q3.x, q3.y}, (f32x2){q3.z, q3.w}};

    const f32x2* w2 = (const f32x2*)Wc1;   // Wc1 rows are 16 floats, 8B aligned
    float a2 = bc2[0];
    #pragma unroll
    for (int i = 0; i < 16; ++i) {
        f32x2 u2 = (f32x2){0.f, 0.f};
        #pragma unroll
        for (int n2 = 0; n2 < 8; ++n2) u2 += w2[i * 8 + n2] * zv2[n2];  // v_pk_fma_f32
        float u = u2.x + u2.y + bc1p[i];
        u = fmaxf(u, 0.f);
        a2 = fmaf(Wc2[i], u, a2);
    }

    float2 ph = ((const float2*)phenos)[r];
    out[r] = ph.x + ph.y + a2;
}

// ---------------------------------------------------------------------------
extern "C" void kernel_launch(void* const* d_in, const int* in_sizes, int n_in,
                              void* d_out, int out_size, void* d_ws, size_t ws_size,
                              hipStream_t stream) {
    const int*   x      = (const int*)  d_in[0];
    const float* phenos = (const float*)d_in[1];
    const float* emb    = (const float*)d_in[2];
    const float* W1     = (const float*)d_in[3];
    const float* b1     = (const float*)d_in[4];
    const float* W2     = (const float*)d_in[5];
    const float* b2     = (const float*)d_in[6];
    const float* W3     = (const float*)d_in[7];
    const float* b3     = (const float*)d_in[8];
    const float* BW     = (const float*)d_in[9];
    const float* BD     = (const float*)d_in[10];
    const float* Boff   = (const float*)d_in[11];
    const float* Wc1    = (const float*)d_in[12];
    const float* bc1    = (const float*)d_in[13];
    const float* Wc2    = (const float*)d_in[14];
    const float* bc2    = (const float*)d_in[15];
    float* out = (float*)d_out;

    // ws layout (bytes): Bhi[0,8192) | bc1p[8192,8256) | T[8256, +1.28MB)
    char* wsb = (char*)d_ws;
    short* Bhi  = (short*)(wsb);
    float* bc1p = (float*)(wsb + 8192);
    float* T    = (float*)(wsb + 8256);

    prep_kernel<<<80, 256, 0, stream>>>(emb, W1, b1, W2, b2, W3, b3, BW, BD,
                                        Wc1, bc1, Boff, T, Bhi, bc1p);
    main_kernel<<<NB / 256, 256, 0, stream>>>(x, phenos, T, Bhi, bc1p, Wc1, Wc2, bc2, out);
}